// Round 2
// baseline (1759.021 us; speedup 1.0000x reference)
//
#include <hip/hip_runtime.h>

typedef _Float16 f16;
typedef _Float16 f16x2 __attribute__((ext_vector_type(2)));
typedef _Float16 f16x4 __attribute__((ext_vector_type(4)));
typedef _Float16 f16x8 __attribute__((ext_vector_type(8)));
typedef float f32x4 __attribute__((ext_vector_type(4)));

#define NB 256
#define NT 1024
#define ND 256
#define NU 128
#define NSIG 20
#define N3U 384
#define BT (NB * NT)

// xproj GEMM tile
#define BM 128
#define BN 128
#define BK 32
#define LDK 40             // padded LDS leading dim (f16): 2-way bank alias only

// recur
#define RB 4               // batches per block
#define RTHREADS 512

static __device__ __forceinline__ float sigmoid_fast(float x) {
    return __builtin_amdgcn_rcpf(1.f + __expf(-x));
}
static __device__ __forceinline__ float tanh_fast(float x) {
    return 1.f - 2.f * __builtin_amdgcn_rcpf(__expf(2.f * x) + 1.f);
}

// ---------------------------------------------------------------------------
// Kernel 1: x_proj = inputs @ input_kernel   [BT,256] @ [256,384] -> f16 [BT,384]
// UNCHANGED from verified R1 version.
// ---------------------------------------------------------------------------
__global__ __launch_bounds__(256) void xproj_gemm(
    const float* __restrict__ A,   // [BT, 256]
    const float* __restrict__ Wk,  // [256, 384]
    f16* __restrict__ out)         // [BT, 384]
{
    const int n0 = blockIdx.x * BN;
    const int m0 = blockIdx.y * BM;
    const int tid = threadIdx.x;
    const int lane = tid & 63;
    const int w = tid >> 6;
    const int mm = lane & 15;
    const int q = lane >> 4;
    const int wr = w >> 1;         // wave row (0..1) -> 64 rows
    const int wc = w & 1;          // wave col (0..1) -> 64 cols

    __shared__ __align__(16) f16 sA[BM * LDK];   // 10 KB, [row][k]
    __shared__ __align__(16) f16 sB[BN * LDK];   // 10 KB, [col][k]

    f32x4 acc[4][4];
    #pragma unroll
    for (int i = 0; i < 4; ++i)
        #pragma unroll
        for (int j = 0; j < 4; ++j)
            acc[i][j] = (f32x4){0.f, 0.f, 0.f, 0.f};

    const int ar = tid >> 1;           // A row 0..127
    const int ac = (tid & 1) * 16;     // A k-offset 0/16
    const int bn = tid >> 1;           // B col 0..127
    const int bk = (tid & 1) * 16;     // B k-offset 0/16

    for (int kt = 0; kt < ND; kt += BK) {
        const float* ap = A + (size_t)(m0 + ar) * ND + kt + ac;
        const float4 a0 = *(const float4*)(ap + 0);
        const float4 a1 = *(const float4*)(ap + 4);
        const float4 a2 = *(const float4*)(ap + 8);
        const float4 a3 = *(const float4*)(ap + 12);

        f16x8 bv0, bv1;
        #pragma unroll
        for (int i = 0; i < 8; ++i)
            bv0[i] = (f16)Wk[(size_t)(kt + bk + i) * N3U + n0 + bn];
        #pragma unroll
        for (int i = 0; i < 8; ++i)
            bv1[i] = (f16)Wk[(size_t)(kt + bk + 8 + i) * N3U + n0 + bn];

        f16x8 av0, av1;
        av0[0]=(f16)a0.x; av0[1]=(f16)a0.y; av0[2]=(f16)a0.z; av0[3]=(f16)a0.w;
        av0[4]=(f16)a1.x; av0[5]=(f16)a1.y; av0[6]=(f16)a1.z; av0[7]=(f16)a1.w;
        av1[0]=(f16)a2.x; av1[1]=(f16)a2.y; av1[2]=(f16)a2.z; av1[3]=(f16)a2.w;
        av1[4]=(f16)a3.x; av1[5]=(f16)a3.y; av1[6]=(f16)a3.z; av1[7]=(f16)a3.w;

        *(f16x8*)(sA + ar * LDK + ac)     = av0;
        *(f16x8*)(sA + ar * LDK + ac + 8) = av1;
        *(f16x8*)(sB + bn * LDK + bk)     = bv0;
        *(f16x8*)(sB + bn * LDK + bk + 8) = bv1;

        __syncthreads();

        f16x8 afrag[4], bfrag[4];
        #pragma unroll
        for (int mi = 0; mi < 4; ++mi)
            afrag[mi] = *(const f16x8*)(sA + (wr * 64 + mi * 16 + mm) * LDK + q * 8);
        #pragma unroll
        for (int ni = 0; ni < 4; ++ni)
            bfrag[ni] = *(const f16x8*)(sB + (wc * 64 + ni * 16 + mm) * LDK + q * 8);

        #pragma unroll
        for (int mi = 0; mi < 4; ++mi)
            #pragma unroll
            for (int ni = 0; ni < 4; ++ni)
                acc[mi][ni] = __builtin_amdgcn_mfma_f32_16x16x32_f16(
                    afrag[mi], bfrag[ni], acc[mi][ni], 0, 0, 0);

        __syncthreads();
    }

    #pragma unroll
    for (int mi = 0; mi < 4; ++mi) {
        #pragma unroll
        for (int ni = 0; ni < 4; ++ni) {
            #pragma unroll
            for (int r = 0; r < 4; ++r) {
                const int row = m0 + wr * 64 + mi * 16 + q * 4 + r;
                const int col = n0 + wc * 64 + ni * 16 + mm;
                out[(size_t)row * N3U + col] = (f16)acc[mi][ni][r];
            }
        }
    }
}

// ---------------------------------------------------------------------------
// Kernel 2: f = sigmoid(signatures @ forget_kernel + b_f) -> f16 [BT,128]
// UNCHANGED from verified R1 version.
// ---------------------------------------------------------------------------
__global__ __launch_bounds__(256) void fgate_kernel(
    const float* __restrict__ sig,
    const float* __restrict__ Wf,
    const float* __restrict__ bias,
    f16* __restrict__ fout)
{
    __shared__ float sWf[NSIG * NU];   // 10 KB
    __shared__ float sSig[8 * NSIG];   // 640 B
    const int tid = threadIdx.x;
    const int bt0 = blockIdx.x * 8;

    for (int i = tid; i < NSIG * NU; i += 256)
        sWf[i] = Wf[i];
    if (tid < 8 * NSIG)
        sSig[tid] = sig[(size_t)bt0 * NSIG + tid];
    __syncthreads();

    const int r = tid >> 5;            // local bt row 0..7
    const int u0 = (tid & 31) * 4;     // u 0..124

    float a0 = bias[NU + u0 + 0];
    float a1 = bias[NU + u0 + 1];
    float a2 = bias[NU + u0 + 2];
    float a3 = bias[NU + u0 + 3];
    #pragma unroll
    for (int s = 0; s < NSIG; ++s) {
        const float sv = sSig[r * NSIG + s];
        const float4 wv = *(const float4*)(&sWf[s * NU + u0]);
        a0 += sv * wv.x; a1 += sv * wv.y; a2 += sv * wv.z; a3 += sv * wv.w;
    }
    f16x4 o;
    o[0] = (f16)sigmoid_fast(a0);
    o[1] = (f16)sigmoid_fast(a1);
    o[2] = (f16)sigmoid_fast(a2);
    o[3] = (f16)sigmoid_fast(a3);
    *(f16x4*)(&fout[(size_t)(bt0 + r) * NU + u0]) = o;
}

// ---------------------------------------------------------------------------
// Kernel 3 (REWRITTEN): recurrence via MFMA, 4 batches/block, 64 blocks,
// 512 threads (8 waves).
//   - Wr preloaded ONCE into registers as MFMA B-fragments (12 f16x8/lane):
//     zero per-step weight traffic.
//   - H [16 rows x 136 pad] f16 in LDS (rows 4..15 permanently zero).
//   - Per step: ph1 = 4 ds_read_b128 (A-frags) + 12 MFMA + masked G-write;
//     barrier; ph2 = 1 cell/thread activation (3 G reads, 8 trans), H + out
//     write; barrier. x/f register-prefetched 2 steps ahead.
//   - Fragment mappings identical to the verified xproj kernel:
//     A: row=lane&15, k=(lane>>4)*8+i;  B: col=lane&15, same k;
//     C/D: col=lane&15, row=(lane>>4)*4+r.
// ---------------------------------------------------------------------------
__global__ __launch_bounds__(RTHREADS, 2) void recur_kernel(
    const f16* __restrict__ xp,      // [BT, 384]
    const f16* __restrict__ fg,      // [BT, 128]
    const float* __restrict__ Wr,    // [128, 384]
    const float* __restrict__ bias,  // [512]
    float* __restrict__ out)         // [BT, 128]
{
    const int tid = threadIdx.x;
    const int lane = tid & 63;
    const int w = tid >> 6;          // wave 0..7
    const int ml = lane & 15;        // row (A) / col (B, C/D) within tile
    const int kg = lane >> 4;        // k-group 0..3
    const int b0 = blockIdx.x * RB;

    // activation mapping: one (batch, u) cell per thread
    const int ab = tid >> 7;         // batch 0..3
    const int au = tid & 127;        // u 0..127

    __shared__ __align__(16) f16 H[16 * 136];    // 4.25 KB, padded stride 136
    __shared__ __align__(16) float G[4 * 388];   // 6.1 KB, gate rows 0..3

    // zero H (rows 4..15 stay zero forever -> garbage-free A operand)
    for (int i = tid; i < 16 * 136; i += RTHREADS) H[i] = (f16)0.f;

    // ---- Wr -> register B-fragments. wave w owns n-tiles j=0..2, n0=w*48+j*16
    f16x8 wrv[3][4];
    #pragma unroll
    for (int j = 0; j < 3; ++j) {
        const int n = w * 48 + j * 16 + ml;
        #pragma unroll
        for (int kt = 0; kt < 4; ++kt) {
            #pragma unroll
            for (int i = 0; i < 8; ++i) {
                const int k = kt * 32 + kg * 8 + i;
                wrv[j][kt][i] = (f16)Wr[(size_t)k * N3U + n];
            }
        }
    }

    const float bi = bias[au];
    const float bc = bias[2 * NU + au];
    const float bo = bias[3 * NU + au];
    float cst = 0.f;

    // ---- x/f prefetch ring (depth 2): slot s holds step values for t (t&1==s)
    f16 xi[2], xc[2], xo[2], ffr[2];
    const size_t xrow0 = ((size_t)(b0 + ab) * NT) * N3U + au;
    const size_t frow0 = ((size_t)(b0 + ab) * NT) * NU + au;
    #pragma unroll
    for (int s = 0; s < 2; ++s) {
        xi[s]  = xp[xrow0 + (size_t)s * N3U];
        xc[s]  = xp[xrow0 + (size_t)s * N3U + NU];
        xo[s]  = xp[xrow0 + (size_t)s * N3U + 2 * NU];
        ffr[s] = fg[frow0 + (size_t)s * NU];
    }

    __syncthreads();

    const int hbase = ml * 136 + kg * 8;   // f16 elements
    for (int t = 0; t < NT; ++t) {
        // ---------------- ph1: G = H @ Wr (MFMA) ----------------
        f16x8 af[4];
        #pragma unroll
        for (int kt = 0; kt < 4; ++kt)
            af[kt] = *(const f16x8*)(H + hbase + kt * 32);

        f32x4 acc[3];
        #pragma unroll
        for (int j = 0; j < 3; ++j) acc[j] = (f32x4){0.f, 0.f, 0.f, 0.f};
        #pragma unroll
        for (int kt = 0; kt < 4; ++kt)
            #pragma unroll
            for (int j = 0; j < 3; ++j)
                acc[j] = __builtin_amdgcn_mfma_f32_16x16x32_f16(
                    af[kt], wrv[j][kt], acc[j], 0, 0, 0);

        if (kg == 0) {   // C/D rows (lane>>4)*4+r -> batches 0..3 live in kg==0
            #pragma unroll
            for (int j = 0; j < 3; ++j) {
                const int col = w * 48 + j * 16 + ml;
                #pragma unroll
                for (int r = 0; r < 4; ++r)
                    G[r * 388 + col] = acc[j][r];
            }
        }
        __syncthreads();   // G ready; all H reads for this step drained

        // ---------------- ph2: activation (1 cell/thread) ----------------
        const int s = t & 1;
        const float gi = G[ab * 388 + au]          + (float)xi[s]  + bi;
        const float gc = G[ab * 388 + NU + au]     + (float)xc[s]  + bc;
        const float go = G[ab * 388 + 2 * NU + au] + (float)xo[s]  + bo;
        const float it = sigmoid_fast(gi);
        const float ch = tanh_fast(gc);
        const float ot = sigmoid_fast(go);
        cst = (float)ffr[s] * cst + it * ch;
        const float h = ot * tanh_fast(cst);
        H[ab * 136 + au] = (f16)h;
        out[((size_t)(b0 + ab) * NT + t) * NU + au] = h;

        // refill ring slot with step t+2 (consumed after next barrier pair)
        if (t + 2 < NT) {
            xi[s]  = xp[xrow0 + (size_t)(t + 2) * N3U];
            xc[s]  = xp[xrow0 + (size_t)(t + 2) * N3U + NU];
            xo[s]  = xp[xrow0 + (size_t)(t + 2) * N3U + 2 * NU];
            ffr[s] = fg[frow0 + (size_t)(t + 2) * NU];
        }
        __syncthreads();   // H(t) visible for next step's MFMA; G consumed
    }
}

// ---------------------------------------------------------------------------
extern "C" void kernel_launch(void* const* d_in, const int* in_sizes, int n_in,
                              void* d_out, int out_size, void* d_ws, size_t ws_size,
                              hipStream_t stream) {
    const float* inputs = (const float*)d_in[0];   // [256,1024,256]
    const float* sig    = (const float*)d_in[1];   // [256,1024,20]
    const float* Wk     = (const float*)d_in[2];   // [256,384]
    const float* Wr     = (const float*)d_in[3];   // [128,384]
    const float* Wf     = (const float*)d_in[4];   // [20,128]
    const float* bias   = (const float*)d_in[5];   // [512]
    float* out = (float*)d_out;                    // [256,1024,128]

    f16* xp = (f16*)d_ws;
    f16* fg = (f16*)((char*)d_ws + (size_t)BT * N3U * sizeof(f16));

    xproj_gemm<<<dim3(N3U / BN, BT / BM), 256, 0, stream>>>(inputs, Wk, xp);
    fgate_kernel<<<dim3(BT / 8), 256, 0, stream>>>(sig, Wf, bias, fg);
    recur_kernel<<<dim3(NB / RB), RTHREADS, 0, stream>>>(xp, fg, Wr, bias, out);

    (void)in_sizes; (void)n_in; (void)out_size; (void)ws_size;
}

// Round 3
// 1319.443 us; speedup vs baseline: 1.3332x; 1.3332x over previous
//
#include <hip/hip_runtime.h>

typedef _Float16 f16;
typedef _Float16 f16x2 __attribute__((ext_vector_type(2)));
typedef _Float16 f16x4 __attribute__((ext_vector_type(4)));
typedef _Float16 f16x8 __attribute__((ext_vector_type(8)));
typedef float f32x4 __attribute__((ext_vector_type(4)));

#define NB 256
#define NT 1024
#define ND 256
#define NU 128
#define NSIG 20
#define N3U 384
#define BT (NB * NT)

// xproj GEMM tile
#define BM 128
#define BN 128
#define BK 32
#define LDK 40             // padded LDS leading dim (f16): 2-way bank alias only

// recur
#define RB 4               // batches per block
#define RTHREADS 512
#define RCH 16             // timesteps per register chunk
#define RNCH (NT / RCH)

static __device__ __forceinline__ float sigmoid_fast(float x) {
    return __builtin_amdgcn_rcpf(1.f + __expf(-x));
}
static __device__ __forceinline__ float tanh_fast(float x) {
    return 1.f - 2.f * __builtin_amdgcn_rcpf(__expf(2.f * x) + 1.f);
}

// ---------------------------------------------------------------------------
// Kernel 1: x_proj = inputs @ input_kernel   [BT,256] @ [256,384] -> f16 [BT,384]
// UNCHANGED from verified R1 version.
// ---------------------------------------------------------------------------
__global__ __launch_bounds__(256) void xproj_gemm(
    const float* __restrict__ A,   // [BT, 256]
    const float* __restrict__ Wk,  // [256, 384]
    f16* __restrict__ out)         // [BT, 384]
{
    const int n0 = blockIdx.x * BN;
    const int m0 = blockIdx.y * BM;
    const int tid = threadIdx.x;
    const int lane = tid & 63;
    const int w = tid >> 6;
    const int mm = lane & 15;
    const int q = lane >> 4;
    const int wr = w >> 1;         // wave row (0..1) -> 64 rows
    const int wc = w & 1;          // wave col (0..1) -> 64 cols

    __shared__ __align__(16) f16 sA[BM * LDK];   // 10 KB, [row][k]
    __shared__ __align__(16) f16 sB[BN * LDK];   // 10 KB, [col][k]

    f32x4 acc[4][4];
    #pragma unroll
    for (int i = 0; i < 4; ++i)
        #pragma unroll
        for (int j = 0; j < 4; ++j)
            acc[i][j] = (f32x4){0.f, 0.f, 0.f, 0.f};

    const int ar = tid >> 1;           // A row 0..127
    const int ac = (tid & 1) * 16;     // A k-offset 0/16
    const int bn = tid >> 1;           // B col 0..127
    const int bk = (tid & 1) * 16;     // B k-offset 0/16

    for (int kt = 0; kt < ND; kt += BK) {
        const float* ap = A + (size_t)(m0 + ar) * ND + kt + ac;
        const float4 a0 = *(const float4*)(ap + 0);
        const float4 a1 = *(const float4*)(ap + 4);
        const float4 a2 = *(const float4*)(ap + 8);
        const float4 a3 = *(const float4*)(ap + 12);

        f16x8 bv0, bv1;
        #pragma unroll
        for (int i = 0; i < 8; ++i)
            bv0[i] = (f16)Wk[(size_t)(kt + bk + i) * N3U + n0 + bn];
        #pragma unroll
        for (int i = 0; i < 8; ++i)
            bv1[i] = (f16)Wk[(size_t)(kt + bk + 8 + i) * N3U + n0 + bn];

        f16x8 av0, av1;
        av0[0]=(f16)a0.x; av0[1]=(f16)a0.y; av0[2]=(f16)a0.z; av0[3]=(f16)a0.w;
        av0[4]=(f16)a1.x; av0[5]=(f16)a1.y; av0[6]=(f16)a1.z; av0[7]=(f16)a1.w;
        av1[0]=(f16)a2.x; av1[1]=(f16)a2.y; av1[2]=(f16)a2.z; av1[3]=(f16)a2.w;
        av1[4]=(f16)a3.x; av1[5]=(f16)a3.y; av1[6]=(f16)a3.z; av1[7]=(f16)a3.w;

        *(f16x8*)(sA + ar * LDK + ac)     = av0;
        *(f16x8*)(sA + ar * LDK + ac + 8) = av1;
        *(f16x8*)(sB + bn * LDK + bk)     = bv0;
        *(f16x8*)(sB + bn * LDK + bk + 8) = bv1;

        __syncthreads();

        f16x8 afrag[4], bfrag[4];
        #pragma unroll
        for (int mi = 0; mi < 4; ++mi)
            afrag[mi] = *(const f16x8*)(sA + (wr * 64 + mi * 16 + mm) * LDK + q * 8);
        #pragma unroll
        for (int ni = 0; ni < 4; ++ni)
            bfrag[ni] = *(const f16x8*)(sB + (wc * 64 + ni * 16 + mm) * LDK + q * 8);

        #pragma unroll
        for (int mi = 0; mi < 4; ++mi)
            #pragma unroll
            for (int ni = 0; ni < 4; ++ni)
                acc[mi][ni] = __builtin_amdgcn_mfma_f32_16x16x32_f16(
                    afrag[mi], bfrag[ni], acc[mi][ni], 0, 0, 0);

        __syncthreads();
    }

    #pragma unroll
    for (int mi = 0; mi < 4; ++mi) {
        #pragma unroll
        for (int ni = 0; ni < 4; ++ni) {
            #pragma unroll
            for (int r = 0; r < 4; ++r) {
                const int row = m0 + wr * 64 + mi * 16 + q * 4 + r;
                const int col = n0 + wc * 64 + ni * 16 + mm;
                out[(size_t)row * N3U + col] = (f16)acc[mi][ni][r];
            }
        }
    }
}

// ---------------------------------------------------------------------------
// Kernel 2: f = sigmoid(signatures @ forget_kernel + b_f) -> f16 [BT,128]
// UNCHANGED from verified R1 version.
// ---------------------------------------------------------------------------
__global__ __launch_bounds__(256) void fgate_kernel(
    const float* __restrict__ sig,
    const float* __restrict__ Wf,
    const float* __restrict__ bias,
    f16* __restrict__ fout)
{
    __shared__ float sWf[NSIG * NU];   // 10 KB
    __shared__ float sSig[8 * NSIG];   // 640 B
    const int tid = threadIdx.x;
    const int bt0 = blockIdx.x * 8;

    for (int i = tid; i < NSIG * NU; i += 256)
        sWf[i] = Wf[i];
    if (tid < 8 * NSIG)
        sSig[tid] = sig[(size_t)bt0 * NSIG + tid];
    __syncthreads();

    const int r = tid >> 5;            // local bt row 0..7
    const int u0 = (tid & 31) * 4;     // u 0..124

    float a0 = bias[NU + u0 + 0];
    float a1 = bias[NU + u0 + 1];
    float a2 = bias[NU + u0 + 2];
    float a3 = bias[NU + u0 + 3];
    #pragma unroll
    for (int s = 0; s < NSIG; ++s) {
        const float sv = sSig[r * NSIG + s];
        const float4 wv = *(const float4*)(&sWf[s * NU + u0]);
        a0 += sv * wv.x; a1 += sv * wv.y; a2 += sv * wv.z; a3 += sv * wv.w;
    }
    f16x4 o;
    o[0] = (f16)sigmoid_fast(a0);
    o[1] = (f16)sigmoid_fast(a1);
    o[2] = (f16)sigmoid_fast(a2);
    o[3] = (f16)sigmoid_fast(a3);
    *(f16x4*)(&fout[(size_t)(bt0 + r) * NU + u0]) = o;
}

// ---------------------------------------------------------------------------
// Kernel 3 (R3): MFMA recurrence, 4 batches/block, 64 blocks, 512 threads.
// Change vs R2: NO global memory ops inside the per-step loop.
//   - x/f for a 16-step chunk loaded into registers at chunk top (64 scalar
//     f16 loads, coalesced) -> drained ONCE at the chunk's first barrier,
//     not per step.
//   - h accumulated in static-indexed hbuf[16] regs (chunk loop fully
//     unrolled), flushed once per chunk.
// Per-step body is now pure LDS + MFMA + VALU, so the compiler's
// vmcnt(0)-before-barrier drain costs nothing per step.
// ---------------------------------------------------------------------------
__global__ __launch_bounds__(RTHREADS, 2) void recur_kernel(
    const f16* __restrict__ xp,      // [BT, 384]
    const f16* __restrict__ fg,      // [BT, 128]
    const float* __restrict__ Wr,    // [128, 384]
    const float* __restrict__ bias,  // [512]
    float* __restrict__ out)         // [BT, 128]
{
    const int tid = threadIdx.x;
    const int lane = tid & 63;
    const int w = tid >> 6;          // wave 0..7
    const int ml = lane & 15;        // row (A) / col (B, C/D) within tile
    const int kg = lane >> 4;        // k-group 0..3
    const int b0 = blockIdx.x * RB;

    // activation mapping: one (batch, u) cell per thread
    const int ab = tid >> 7;         // batch 0..3
    const int au = tid & 127;        // u 0..127

    __shared__ __align__(16) f16 H[16 * 136];    // 4.25 KB, padded stride 136
    __shared__ __align__(16) float G[4 * 388];   // 6.1 KB, gate rows 0..3

    // zero H (rows 4..15 stay zero forever -> garbage-free A operand)
    for (int i = tid; i < 16 * 136; i += RTHREADS) H[i] = (f16)0.f;

    // ---- Wr -> register B-fragments. wave w owns n-tiles j=0..2, n0=w*48+j*16
    f16x8 wrv[3][4];
    #pragma unroll
    for (int j = 0; j < 3; ++j) {
        const int n = w * 48 + j * 16 + ml;
        #pragma unroll
        for (int kt = 0; kt < 4; ++kt) {
            #pragma unroll
            for (int i = 0; i < 8; ++i) {
                const int k = kt * 32 + kg * 8 + i;
                wrv[j][kt][i] = (f16)Wr[(size_t)k * N3U + n];
            }
        }
    }

    const float bi = bias[au];
    const float bc = bias[2 * NU + au];
    const float bo = bias[3 * NU + au];
    float cst = 0.f;

    const size_t xrow0 = ((size_t)(b0 + ab) * NT) * N3U + au;
    const size_t frow0 = ((size_t)(b0 + ab) * NT) * NU + au;
    const size_t orow0 = ((size_t)(b0 + ab) * NT) * NU + au;

    __syncthreads();

    const int hbase = ml * 136 + kg * 8;   // f16 elements

    for (int c = 0; c < RNCH; ++c) {
        const int tbase = c * RCH;

        // ---- chunk register prefetch: 64 coalesced scalar f16 loads.
        // Drained once at the first barrier below; values live in regs.
        f16 xiv[RCH], xcv[RCH], xov[RCH], fv[RCH];
        #pragma unroll
        for (int tt = 0; tt < RCH; ++tt) {
            const size_t xr = xrow0 + (size_t)(tbase + tt) * N3U;
            xiv[tt] = xp[xr];
            xcv[tt] = xp[xr + NU];
            xov[tt] = xp[xr + 2 * NU];
            fv[tt]  = fg[frow0 + (size_t)(tbase + tt) * NU];
        }

        float hbuf[RCH];

        #pragma unroll
        for (int tt = 0; tt < RCH; ++tt) {
            // ---------------- ph1: G = H @ Wr (MFMA) ----------------
            f16x8 af[4];
            #pragma unroll
            for (int kt = 0; kt < 4; ++kt)
                af[kt] = *(const f16x8*)(H + hbase + kt * 32);

            f32x4 acc[3];
            #pragma unroll
            for (int j = 0; j < 3; ++j) acc[j] = (f32x4){0.f, 0.f, 0.f, 0.f};
            #pragma unroll
            for (int kt = 0; kt < 4; ++kt)
                #pragma unroll
                for (int j = 0; j < 3; ++j)
                    acc[j] = __builtin_amdgcn_mfma_f32_16x16x32_f16(
                        af[kt], wrv[j][kt], acc[j], 0, 0, 0);

            if (kg == 0) {   // C/D rows 0..3 = batches live in kg==0 lanes
                #pragma unroll
                for (int j = 0; j < 3; ++j) {
                    const int col = w * 48 + j * 16 + ml;
                    #pragma unroll
                    for (int r = 0; r < 4; ++r)
                        G[r * 388 + col] = acc[j][r];
                }
            }
            __syncthreads();   // G ready; H reads for this step drained

            // ---------------- ph2: activation (1 cell/thread) ----------------
            const float gi = G[ab * 388 + au]          + (float)xiv[tt] + bi;
            const float gc = G[ab * 388 + NU + au]     + (float)xcv[tt] + bc;
            const float go = G[ab * 388 + 2 * NU + au] + (float)xov[tt] + bo;
            const float it = sigmoid_fast(gi);
            const float ch = tanh_fast(gc);
            const float ot = sigmoid_fast(go);
            cst = (float)fv[tt] * cst + it * ch;
            const float h = ot * tanh_fast(cst);
            H[ab * 136 + au] = (f16)h;
            hbuf[tt] = h;
            __syncthreads();   // H(t) visible for next step's MFMA; G consumed
        }

        // ---- flush chunk h to global (drained at next chunk's first barrier)
        #pragma unroll
        for (int tt = 0; tt < RCH; ++tt)
            out[orow0 + (size_t)(tbase + tt) * NU] = hbuf[tt];
    }
}

// ---------------------------------------------------------------------------
extern "C" void kernel_launch(void* const* d_in, const int* in_sizes, int n_in,
                              void* d_out, int out_size, void* d_ws, size_t ws_size,
                              hipStream_t stream) {
    const float* inputs = (const float*)d_in[0];   // [256,1024,256]
    const float* sig    = (const float*)d_in[1];   // [256,1024,20]
    const float* Wk     = (const float*)d_in[2];   // [256,384]
    const float* Wr     = (const float*)d_in[3];   // [128,384]
    const float* Wf     = (const float*)d_in[4];   // [20,128]
    const float* bias   = (const float*)d_in[5];   // [512]
    float* out = (float*)d_out;                    // [256,1024,128]

    f16* xp = (f16*)d_ws;
    f16* fg = (f16*)((char*)d_ws + (size_t)BT * N3U * sizeof(f16));

    xproj_gemm<<<dim3(N3U / BN, BT / BM), 256, 0, stream>>>(inputs, Wk, xp);
    fgate_kernel<<<dim3(BT / 8), 256, 0, stream>>>(sig, Wf, bias, fg);
    recur_kernel<<<dim3(NB / RB), RTHREADS, 0, stream>>>(xp, fg, Wr, bias, out);

    (void)in_sizes; (void)n_in; (void)out_size; (void)ws_size;
}